// Round 1
// baseline (181.162 us; speedup 1.0000x reference)
//
#include <hip/hip_runtime.h>
#include <math.h>

#define V_SIZE 100000
#define E_DIM  128
#define B_SIZE 512
#define Q_LEN  32
#define D_LEN  256
#define K_NUM  21

// Kernel params (faithful to the reference's swapped sigma call):
// mus sorted ascending: [-0.95, -0.85, ..., 0.85, 0.95, 1.0]
// sigmas sorted descending: [0.1, 0.001 x 20]  -> k=0 broad, k>=1 sharp

__global__ __launch_bounds__(256) void knrm_main(
    const float* __restrict__ emb,
    const int* __restrict__ q1, const int* __restrict__ d1,
    const int* __restrict__ q2, const int* __restrict__ d2,
    const float* __restrict__ w1, const float* __restrict__ b1,
    const float* __restrict__ w2, const float* __restrict__ b2,
    const float* __restrict__ w3, const float* __restrict__ b3,
    float* __restrict__ logits)
{
    const int b    = blockIdx.x;
    const int pair = blockIdx.y;
    const int t    = threadIdx.x;
    const int* __restrict__ qidx = pair ? q2 : q1;
    const int* __restrict__ didx = pair ? d2 : d1;

    // 8224 floats = 32.9 KB, aliased: phase 1-2 uses first 16 KB as qn[32][128],
    // phase 3 uses all of it as mmx[32][257] (pad 1 -> bank = (q+d)%32, conflict-free)
    __shared__ float smem[Q_LEN * (D_LEN + 1)];
    float (*qn)[E_DIM]       = (float (*)[E_DIM])smem;
    float (*mmx)[D_LEN + 1]  = (float (*)[D_LEN + 1])smem;
    __shared__ float red[Q_LEN][8];
    __shared__ float qscale[Q_LEN];
    __shared__ float lp[K_NUM][Q_LEN + 1];   // +1 pad for the k-sum phase
    __shared__ float ko[K_NUM];

    // ---- Phase 1: gather query rows -> LDS, compute row norms, scale.
    const int r = t >> 3;        // 32 rows x 8 threads
    const int c = t & 7;
    {
        int qi = qidx[b * Q_LEN + r];
        qi = min(max(qi, 0), V_SIZE - 1);
        const float4* src = (const float4*)(emb + (size_t)qi * E_DIM) + c * 4;
        float4 v0 = src[0], v1 = src[1], v2 = src[2], v3 = src[3];
        float ss = v0.x*v0.x + v0.y*v0.y + v0.z*v0.z + v0.w*v0.w
                 + v1.x*v1.x + v1.y*v1.y + v1.z*v1.z + v1.w*v1.w
                 + v2.x*v2.x + v2.y*v2.y + v2.z*v2.z + v2.w*v2.w
                 + v3.x*v3.x + v3.y*v3.y + v3.z*v3.z + v3.w*v3.w;
        float4* dst = (float4*)&qn[r][0] + c * 4;
        dst[0] = v0; dst[1] = v1; dst[2] = v2; dst[3] = v3;
        red[r][c] = ss;
    }
    __syncthreads();
    if (t < Q_LEN) {
        float s = 0.f;
        #pragma unroll
        for (int j = 0; j < 8; ++j) s += red[t][j];
        qscale[t] = 1.0f / fmaxf(sqrtf(s), 1e-8f);
    }
    __syncthreads();
    {
        const float sc = qscale[r];
        float4* dst = (float4*)&qn[r][0] + c * 4;
        #pragma unroll
        for (int j = 0; j < 4; ++j) {
            float4 v = dst[j];
            v.x *= sc; v.y *= sc; v.z *= sc; v.w *= sc;
            dst[j] = v;
        }
    }
    __syncthreads();

    // ---- Phase 2: each thread owns one doc row; one global pass accumulating
    // 32 dots (vs LDS-broadcast qn) + its own sumsq. Normalize at the end.
    float dots[Q_LEN];
    #pragma unroll
    for (int q = 0; q < Q_LEN; ++q) dots[q] = 0.f;
    float dss = 0.f;
    {
        int di = didx[b * D_LEN + t];
        di = min(max(di, 0), V_SIZE - 1);
        const float4* drow = (const float4*)(emb + (size_t)di * E_DIM);
        #pragma unroll 2
        for (int e4 = 0; e4 < E_DIM / 4; ++e4) {
            float4 dv = drow[e4];
            dss = fmaf(dv.x, dv.x, fmaf(dv.y, dv.y, fmaf(dv.z, dv.z, fmaf(dv.w, dv.w, dss))));
            #pragma unroll
            for (int q = 0; q < Q_LEN; ++q) {
                const float4 qv = ((const float4*)&qn[q][0])[e4];  // wave-broadcast
                dots[q] = fmaf(dv.x, qv.x, fmaf(dv.y, qv.y, fmaf(dv.z, qv.z, fmaf(dv.w, qv.w, dots[q]))));
            }
        }
    }
    const float rn = 1.0f / fmaxf(sqrtf(dss), 1e-8f);
    __syncthreads();   // everyone done reading qn before we overwrite it with mmx
    #pragma unroll
    for (int q = 0; q < Q_LEN; ++q) mmx[q][t] = dots[q] * rn;
    __syncthreads();

    // ---- Phase 3: Gaussian-kernel pooling. Thread handles (q,k) pairs.
    for (int p = t; p < K_NUM * Q_LEN; p += 256) {
        const int q = p & 31;
        const int k = p >> 5;
        // mu[k], coeff[k] = -0.5/sigma^2
        float mu, cc;
        if (k == 0)       { mu = -0.95f; cc = -0.5f / (0.1f * 0.1f); }
        else if (k == 20) { mu = 1.0f;   cc = -0.5f / (0.001f * 0.001f); }
        else              { mu = 0.1f * (float)k - 0.95f; cc = -0.5f / (0.001f * 0.001f); }
        float s0 = 0.f, s1 = 0.f, s2 = 0.f, s3 = 0.f;
        const float* row = &mmx[q][0];
        #pragma unroll 4
        for (int d = 0; d < D_LEN; d += 4) {
            float x0 = row[d + 0] - mu;
            float x1 = row[d + 1] - mu;
            float x2 = row[d + 2] - mu;
            float x3 = row[d + 3] - mu;
            s0 += __expf(x0 * x0 * cc);
            s1 += __expf(x1 * x1 * cc);
            s2 += __expf(x2 * x2 * cc);
            s3 += __expf(x3 * x3 * cc);
        }
        lp[k][q] = log1pf((s0 + s1) + (s2 + s3));
    }
    __syncthreads();

    // ---- k_out[k] = sum_q log1p(phi_sum)
    if (t < K_NUM) {
        float s = 0.f;
        #pragma unroll
        for (int q = 0; q < Q_LEN; ++q) s += lp[t][q];
        ko[t] = s;
    }
    __syncthreads();

    // ---- MLP 21 -> 10 -> 5 -> 1 (tiny; thread 0)
    if (t == 0) {
        float x1v[10];
        #pragma unroll
        for (int i = 0; i < 10; ++i) {
            float s = b1[i];
            for (int k = 0; k < K_NUM; ++k) {
                float v = ko[k] > 0.f ? ko[k] : 0.f;
                s = fmaf(v, w1[k * 10 + i], s);
            }
            x1v[i] = s;
        }
        float x2v[5];
        #pragma unroll
        for (int i = 0; i < 5; ++i) {
            float s = b2[i];
            #pragma unroll
            for (int k = 0; k < 10; ++k) {
                float v = x1v[k] > 0.f ? x1v[k] : 0.f;
                s = fmaf(v, w2[k * 5 + i], s);
            }
            x2v[i] = s;
        }
        float s3 = b3[0];
        #pragma unroll
        for (int k = 0; k < 5; ++k) {
            float v = x2v[k] > 0.f ? x2v[k] : 0.f;
            s3 = fmaf(v, w3[k], s3);
        }
        logits[pair * B_SIZE + b] = s3;
    }
}

__global__ void knrm_final(const float* __restrict__ logits, float* __restrict__ out)
{
    const int b = blockIdx.x * blockDim.x + threadIdx.x;
    if (b < B_SIZE) {
        const float dl = logits[b] - logits[B_SIZE + b];
        out[b] = 1.0f / (1.0f + __expf(-dl));
    }
}

extern "C" void kernel_launch(void* const* d_in, const int* in_sizes, int n_in,
                              void* d_out, int out_size, void* d_ws, size_t ws_size,
                              hipStream_t stream)
{
    const float* emb = (const float*)d_in[0];
    const float* w1  = (const float*)d_in[1];
    const float* b1  = (const float*)d_in[2];
    const float* w2  = (const float*)d_in[3];
    const float* b2  = (const float*)d_in[4];
    const float* w3  = (const float*)d_in[5];
    const float* b3  = (const float*)d_in[6];
    const int*   q1  = (const int*)d_in[7];
    const int*   d1  = (const int*)d_in[8];
    const int*   q2  = (const int*)d_in[9];
    const int*   d2  = (const int*)d_in[10];

    float* logits = (float*)d_ws;          // [2][B_SIZE]
    float* out    = (float*)d_out;         // [B_SIZE]

    dim3 grid(B_SIZE, 2);
    knrm_main<<<grid, 256, 0, stream>>>(emb, q1, d1, q2, d2,
                                        w1, b1, w2, b2, w3, b3, logits);
    knrm_final<<<(B_SIZE + 255) / 256, 256, 0, stream>>>(logits, out);
}

// Round 2
// 160.728 us; speedup vs baseline: 1.1271x; 1.1271x over previous
//
#include <hip/hip_runtime.h>
#include <math.h>

#define V_SIZE 100000
#define E_DIM  128
#define B_SIZE 512
#define Q_LEN  32
#define D_LEN  256
#define K_NUM  21

// Kernel params (faithful to the reference's swapped sigma call):
// mus sorted ascending: [-0.95, -0.85, ..., 0.85, 0.95, 1.0]
// sigmas sorted descending: [0.1, 0.001 x 20]  -> k=0 broad, k>=1 sharp
//
// Exactness of the nearest-bin trick: sharp sigma = 1e-3 -> exp underflows to
// 0.0f (incl. subnormals) once 0.5*x^2/sigma^2 > ~104, i.e. |x| > 0.01443.
// Sharp mus are >= 0.05 apart, so at most ONE sharp bin is nonzero per mm;
// summing broad + nearest-sharp is bit-identical to summing all 21 bins.

__global__ __launch_bounds__(128, 2) void knrm_main(
    const float* __restrict__ emb,
    const int* __restrict__ q1, const int* __restrict__ d1,
    const int* __restrict__ q2, const int* __restrict__ d2,
    const float* __restrict__ w1, const float* __restrict__ b1,
    const float* __restrict__ w2, const float* __restrict__ b2,
    const float* __restrict__ w3, const float* __restrict__ b3,
    float* __restrict__ logits)
{
    const int b    = blockIdx.x;
    const int pair = blockIdx.y;
    const int t    = threadIdx.x;            // 0..127
    const int* __restrict__ qidx = pair ? q2 : q1;
    const int* __restrict__ didx = pair ? d2 : d1;

    // 8224 floats = 32.9 KB, aliased: phases 1-2 use first 16 KB as qn[32][128],
    // phase 3 uses all of it as mmx[32][257] (pad 1 -> bank = (q+d)%32, conflict-free)
    __shared__ float smem[Q_LEN * (D_LEN + 1)];
    float (*qn)[E_DIM]      = (float (*)[E_DIM])smem;
    float (*mmx)[D_LEN + 1] = (float (*)[D_LEN + 1])smem;
    __shared__ float red[Q_LEN][4];
    __shared__ float qscale[Q_LEN];
    __shared__ float phis[Q_LEN][24];        // [q][k] accumulators (21 used)
    __shared__ float lp[K_NUM][Q_LEN + 1];
    __shared__ float ko[K_NUM];

    // ---- Phase 0: zero the phi accumulators (LDS atomics target)
    for (int i = t; i < Q_LEN * 24; i += 128) ((float*)phis)[i] = 0.f;

    // ---- Phase 1: gather query rows -> LDS, compute row norms, scale.
    const int r = t >> 2;        // 32 rows x 4 threads
    const int c = t & 3;
    {
        int qi = qidx[b * Q_LEN + r];
        qi = min(max(qi, 0), V_SIZE - 1);
        const float4* src = (const float4*)(emb + (size_t)qi * E_DIM) + c * 8;
        float ss = 0.f;
        float4* dst = (float4*)&qn[r][0] + c * 8;
        #pragma unroll
        for (int j = 0; j < 8; ++j) {
            float4 v = src[j];
            ss += v.x*v.x + v.y*v.y + v.z*v.z + v.w*v.w;
            dst[j] = v;
        }
        red[r][c] = ss;
    }
    __syncthreads();
    if (t < Q_LEN) {
        float s = red[t][0] + red[t][1] + red[t][2] + red[t][3];
        qscale[t] = 1.0f / fmaxf(sqrtf(s), 1e-8f);
    }
    __syncthreads();
    {
        const float sc = qscale[r];
        float4* dst = (float4*)&qn[r][0] + c * 8;
        #pragma unroll
        for (int j = 0; j < 8; ++j) {
            float4 v = dst[j];
            v.x *= sc; v.y *= sc; v.z *= sc; v.w *= sc;
            dst[j] = v;
        }
    }
    __syncthreads();

    // ---- Phase 2: each thread owns TWO doc rows (t and t+128); one global
    // pass accumulating 2x32 dots vs LDS-broadcast qn. Each broadcast qv
    // feeds 8 FMAs (2 docs) -> half the LDS return-bus bytes per FLOP.
    float dots0[Q_LEN], dots1[Q_LEN];
    #pragma unroll
    for (int q = 0; q < Q_LEN; ++q) { dots0[q] = 0.f; dots1[q] = 0.f; }
    float dss0 = 0.f, dss1 = 0.f;
    {
        int di0 = didx[b * D_LEN + t];
        int di1 = didx[b * D_LEN + t + 128];
        di0 = min(max(di0, 0), V_SIZE - 1);
        di1 = min(max(di1, 0), V_SIZE - 1);
        const float4* dr0 = (const float4*)(emb + (size_t)di0 * E_DIM);
        const float4* dr1 = (const float4*)(emb + (size_t)di1 * E_DIM);
        #pragma unroll 2
        for (int e4 = 0; e4 < E_DIM / 4; ++e4) {
            const float4 a0 = dr0[e4];
            const float4 a1 = dr1[e4];
            dss0 = fmaf(a0.x, a0.x, fmaf(a0.y, a0.y, fmaf(a0.z, a0.z, fmaf(a0.w, a0.w, dss0))));
            dss1 = fmaf(a1.x, a1.x, fmaf(a1.y, a1.y, fmaf(a1.z, a1.z, fmaf(a1.w, a1.w, dss1))));
            #pragma unroll
            for (int q = 0; q < Q_LEN; ++q) {
                const float4 qv = ((const float4*)&qn[q][0])[e4];  // wave-broadcast
                dots0[q] = fmaf(a0.x, qv.x, fmaf(a0.y, qv.y, fmaf(a0.z, qv.z, fmaf(a0.w, qv.w, dots0[q]))));
                dots1[q] = fmaf(a1.x, qv.x, fmaf(a1.y, qv.y, fmaf(a1.z, qv.z, fmaf(a1.w, qv.w, dots1[q]))));
            }
        }
    }
    const float rn0 = 1.0f / fmaxf(sqrtf(dss0), 1e-8f);
    const float rn1 = 1.0f / fmaxf(sqrtf(dss1), 1e-8f);
    __syncthreads();   // everyone done reading qn before we overwrite it with mmx
    #pragma unroll
    for (int q = 0; q < Q_LEN; ++q) {
        mmx[q][t]       = dots0[q] * rn0;
        mmx[q][t + 128] = dots1[q] * rn1;
    }
    __syncthreads();

    // ---- Phase 3: pooling with the nearest-bin trick (2 exps per mm).
    {
        const int q    = t & 31;
        const int part = t >> 5;             // 0..3, 64 docs each
        const float cc0 = -0.5f / (0.1f * 0.1f);
        const float ccs = -0.5f / (0.001f * 0.001f);
        const float* row = &mmx[q][0] + part * 64;
        float e0sum = 0.f;
        #pragma unroll 4
        for (int i = 0; i < 64; ++i) {
            const float mm = row[i];
            const float x0 = mm + 0.95f;               // broad bin (mu=-0.95, sigma=0.1)
            e0sum += __expf(x0 * x0 * cc0);
            float g = rintf((mm + 0.85f) * 10.f);      // nearest sharp grid bin
            g = fminf(fmaxf(g, 0.f), 18.f);
            float mu = fmaf(g, 0.1f, -0.85f);
            int ks = (int)g + 1;
            if (mm > 0.975f) { mu = 1.0f; ks = 20; }   // mu=1.0 bin region
            const float xs = mm - mu;
            const float es = __expf(xs * xs * ccs);
            if (es > 0.f) atomicAdd(&phis[q][ks], es);
        }
        atomicAdd(&phis[q][0], e0sum);
    }
    __syncthreads();

    // ---- lp[k][q] = log1p(phi_sum), then k_out[k] = sum_q
    for (int p = t; p < K_NUM * Q_LEN; p += 128) {
        const int q = p & 31;
        const int k = p >> 5;
        lp[k][q] = log1pf(phis[q][k]);
    }
    __syncthreads();
    if (t < K_NUM) {
        float s = 0.f;
        #pragma unroll
        for (int q = 0; q < Q_LEN; ++q) s += lp[t][q];
        ko[t] = s;
    }
    __syncthreads();

    // ---- MLP 21 -> 10 -> 5 -> 1 (tiny; thread 0)
    if (t == 0) {
        float x1v[10];
        #pragma unroll
        for (int i = 0; i < 10; ++i) {
            float s = b1[i];
            for (int k = 0; k < K_NUM; ++k) {
                float v = ko[k] > 0.f ? ko[k] : 0.f;
                s = fmaf(v, w1[k * 10 + i], s);
            }
            x1v[i] = s;
        }
        float x2v[5];
        #pragma unroll
        for (int i = 0; i < 5; ++i) {
            float s = b2[i];
            #pragma unroll
            for (int k = 0; k < 10; ++k) {
                float v = x1v[k] > 0.f ? x1v[k] : 0.f;
                s = fmaf(v, w2[k * 5 + i], s);
            }
            x2v[i] = s;
        }
        float s3 = b3[0];
        #pragma unroll
        for (int k = 0; k < 5; ++k) {
            float v = x2v[k] > 0.f ? x2v[k] : 0.f;
            s3 = fmaf(v, w3[k], s3);
        }
        logits[pair * B_SIZE + b] = s3;
    }
}

__global__ void knrm_final(const float* __restrict__ logits, float* __restrict__ out)
{
    const int b = blockIdx.x * blockDim.x + threadIdx.x;
    if (b < B_SIZE) {
        const float dl = logits[b] - logits[B_SIZE + b];
        out[b] = 1.0f / (1.0f + __expf(-dl));
    }
}

extern "C" void kernel_launch(void* const* d_in, const int* in_sizes, int n_in,
                              void* d_out, int out_size, void* d_ws, size_t ws_size,
                              hipStream_t stream)
{
    const float* emb = (const float*)d_in[0];
    const float* w1  = (const float*)d_in[1];
    const float* b1  = (const float*)d_in[2];
    const float* w2  = (const float*)d_in[3];
    const float* b2  = (const float*)d_in[4];
    const float* w3  = (const float*)d_in[5];
    const float* b3  = (const float*)d_in[6];
    const int*   q1  = (const int*)d_in[7];
    const int*   d1  = (const int*)d_in[8];
    const int*   q2  = (const int*)d_in[9];
    const int*   d2  = (const int*)d_in[10];

    float* logits = (float*)d_ws;          // [2][B_SIZE]
    float* out    = (float*)d_out;         // [B_SIZE]

    dim3 grid(B_SIZE, 2);
    knrm_main<<<grid, 128, 0, stream>>>(emb, q1, d1, q2, d2,
                                        w1, b1, w2, b2, w3, b3, logits);
    knrm_final<<<(B_SIZE + 255) / 256, 256, 0, stream>>>(logits, out);
}

// Round 3
// 129.850 us; speedup vs baseline: 1.3952x; 1.2378x over previous
//
#include <hip/hip_runtime.h>
#include <math.h>

#define V_SIZE 100000
#define E_DIM  128
#define B_SIZE 512
#define Q_LEN  32
#define D_LEN  256
#define K_NUM  21
#define ASTR   136   // fp16 row stride (128 + 8 pad -> 4-bank row shift, <=2-way conflicts)

// Kernel params (faithful to the reference's swapped sigma call):
// mus ascending: [-0.95, -0.85, ..., 0.85, 0.95, 1.0]
// sigmas descending: [0.1, 0.001 x 20]  -> k=0 broad, k>=1 sharp.
//
// Nearest-bin exactness: sharp sigma=1e-3 -> exp underflows to 0.0f once
// |mm-mu| > 0.01443; sharp mus are >=0.05 apart -> at most ONE sharp bin
// nonzero per mm. broad + nearest-sharp == all 21 bins, bit-exact.
//
// fp16-split matmul exactness: a = hi + lo (both fp16, |lo| <= 2^-11|a|,
// lo repr err <= 2^-22|a|). hi*hi + hi*lo + lo*hi drops only lo*lo
// (<=2^-22|a||b|). After /(||q|| ||d||), mm error ~1e-6 — fp32-class.

typedef _Float16 half8_t __attribute__((ext_vector_type(8)));
typedef float    float4_t __attribute__((ext_vector_type(4)));

__global__ __launch_bounds__(256, 4) void knrm_main(
    const float* __restrict__ emb,
    const int* __restrict__ q1, const int* __restrict__ d1,
    const int* __restrict__ q2, const int* __restrict__ d2,
    const float* __restrict__ w1, const float* __restrict__ b1,
    const float* __restrict__ w2, const float* __restrict__ b2,
    const float* __restrict__ w3, const float* __restrict__ b3,
    float* __restrict__ logits)
{
    const int b    = blockIdx.x;
    const int pair = blockIdx.y;
    const int t    = threadIdx.x;            // 0..255
    const int* __restrict__ qidx = pair ? q2 : q1;
    const int* __restrict__ didx = pair ? d2 : d1;

    __shared__ __align__(16) _Float16 Ah[Q_LEN * ASTR];   // queries hi
    __shared__ __align__(16) _Float16 Al[Q_LEN * ASTR];   // queries lo
    __shared__ __align__(16) _Float16 Bh[32 * ASTR];      // doc chunk hi
    __shared__ __align__(16) _Float16 Bl[32 * ASTR];      // doc chunk lo
    __shared__ float rnq[Q_LEN];
    __shared__ float rnd_s[32];
    __shared__ float phis[Q_LEN][22];        // k = 0..20
    __shared__ float ko[K_NUM];

    const int lane = t & 63;
    const int w    = t >> 6;                 // wave 0..3
    const int quad = lane >> 4;
    const int l15  = lane & 15;
    const int qt   = w >> 1;                 // q-tile (0..1), wave-fixed
    const int dt   = w & 1;                  // d-tile within chunk (0..1)

    // ---- phis init
    for (int i = t; i < Q_LEN * 22; i += 256) ((float*)phis)[i] = 0.f;

    // ---- doc indices for all 8 chunks + prefetch chunk 0
    const int drow = t >> 3;                 // 0..31 (row within chunk)
    const int dcol = (t & 7) * 4;            // float4 index within row
    int dix[8];
    #pragma unroll
    for (int c = 0; c < 8; ++c) {
        int di = didx[b * D_LEN + c * 32 + drow];
        dix[c] = min(max(di, 0), V_SIZE - 1);
    }
    float4 pref[4];
    {
        const float4* dr = (const float4*)(emb + (size_t)dix[0] * E_DIM) + dcol;
        pref[0] = dr[0]; pref[1] = dr[1]; pref[2] = dr[2]; pref[3] = dr[3];
    }

    // ---- Phase 1: queries -> fp16 hi/lo in LDS + rnq (shfl-reduced sumsq)
    {
        const int qr = t >> 3;               // 0..31
        const int qc = t & 7;                // col block: 16 floats
        int qi = qidx[b * Q_LEN + qr];
        qi = min(max(qi, 0), V_SIZE - 1);
        const float4* src = (const float4*)(emb + (size_t)qi * E_DIM) + qc * 4;
        float4 v0 = src[0], v1 = src[1], v2 = src[2], v3 = src[3];
        float fv[16] = {v0.x,v0.y,v0.z,v0.w, v1.x,v1.y,v1.z,v1.w,
                        v2.x,v2.y,v2.z,v2.w, v3.x,v3.y,v3.z,v3.w};
        float ss = 0.f;
        half8_t h0, h1, l0, l1;
        #pragma unroll
        for (int j = 0; j < 8; ++j) {
            ss = fmaf(fv[j], fv[j], ss);
            _Float16 h = (_Float16)fv[j];
            h0[j] = h; l0[j] = (_Float16)(fv[j] - (float)h);
        }
        #pragma unroll
        for (int j = 0; j < 8; ++j) {
            ss = fmaf(fv[8 + j], fv[8 + j], ss);
            _Float16 h = (_Float16)fv[8 + j];
            h1[j] = h; l1[j] = (_Float16)(fv[8 + j] - (float)h);
        }
        *(half8_t*)&Ah[qr * ASTR + qc * 16]     = h0;
        *(half8_t*)&Ah[qr * ASTR + qc * 16 + 8] = h1;
        *(half8_t*)&Al[qr * ASTR + qc * 16]     = l0;
        *(half8_t*)&Al[qr * ASTR + qc * 16 + 8] = l1;
        ss += __shfl_xor(ss, 1, 8);
        ss += __shfl_xor(ss, 2, 8);
        ss += __shfl_xor(ss, 4, 8);
        if (qc == 0) rnq[qr] = 1.0f / fmaxf(sqrtf(ss), 1e-8f);
    }
    __syncthreads();

    float rnq4[4];
    #pragma unroll
    for (int r = 0; r < 4; ++r) rnq4[r] = rnq[qt * 16 + quad * 4 + r];

    const float cc0 = -0.5f / (0.1f * 0.1f);
    const float ccs = -0.5f / (0.001f * 0.001f);
    float breg[4] = {0.f, 0.f, 0.f, 0.f};

    // ---- Main loop: 8 chunks of 32 docs
    for (int c = 0; c < 8; ++c) {
        // convert prefetched rows -> Bh/Bl, shfl sumsq -> rnd_s
        {
            float fv[16] = {pref[0].x,pref[0].y,pref[0].z,pref[0].w,
                            pref[1].x,pref[1].y,pref[1].z,pref[1].w,
                            pref[2].x,pref[2].y,pref[2].z,pref[2].w,
                            pref[3].x,pref[3].y,pref[3].z,pref[3].w};
            float ss = 0.f;
            half8_t h0, h1, l0, l1;
            #pragma unroll
            for (int j = 0; j < 8; ++j) {
                ss = fmaf(fv[j], fv[j], ss);
                _Float16 h = (_Float16)fv[j];
                h0[j] = h; l0[j] = (_Float16)(fv[j] - (float)h);
            }
            #pragma unroll
            for (int j = 0; j < 8; ++j) {
                ss = fmaf(fv[8 + j], fv[8 + j], ss);
                _Float16 h = (_Float16)fv[8 + j];
                h1[j] = h; l1[j] = (_Float16)(fv[8 + j] - (float)h);
            }
            const int co = (t & 7) * 16;
            *(half8_t*)&Bh[drow * ASTR + co]     = h0;
            *(half8_t*)&Bh[drow * ASTR + co + 8] = h1;
            *(half8_t*)&Bl[drow * ASTR + co]     = l0;
            *(half8_t*)&Bl[drow * ASTR + co + 8] = l1;
            ss += __shfl_xor(ss, 1, 8);
            ss += __shfl_xor(ss, 2, 8);
            ss += __shfl_xor(ss, 4, 8);
            if ((t & 7) == 0) rnd_s[drow] = 1.0f / fmaxf(sqrtf(ss), 1e-8f);
        }
        __syncthreads();

        // prefetch next chunk under the MFMA
        if (c < 7) {
            const float4* dr = (const float4*)(emb + (size_t)dix[c + 1] * E_DIM) + dcol;
            pref[0] = dr[0]; pref[1] = dr[1]; pref[2] = dr[2]; pref[3] = dr[3];
        }

        // MFMA: this wave's 16x16 tile = (qt, dt) of the 32q x 32d chunk
        float4_t acc = {0.f, 0.f, 0.f, 0.f};
        const int arow = (qt * 16 + l15) * ASTR;
        const int brow = (dt * 16 + l15) * ASTR;
        #pragma unroll
        for (int s = 0; s < 4; ++s) {
            const int kof = s * 32 + quad * 8;
            half8_t ah = *(const half8_t*)&Ah[arow + kof];
            half8_t al = *(const half8_t*)&Al[arow + kof];
            half8_t bh = *(const half8_t*)&Bh[brow + kof];
            half8_t bl = *(const half8_t*)&Bl[brow + kof];
            acc = __builtin_amdgcn_mfma_f32_16x16x32_f16(ah, bh, acc, 0, 0, 0);
            acc = __builtin_amdgcn_mfma_f32_16x16x32_f16(ah, bl, acc, 0, 0, 0);
            acc = __builtin_amdgcn_mfma_f32_16x16x32_f16(al, bh, acc, 0, 0, 0);
        }

        // epilogue: mm -> broad reg-accum + nearest sharp bin atomic
        const float rdv = rnd_s[dt * 16 + l15];
        #pragma unroll
        for (int r = 0; r < 4; ++r) {
            const float mm = acc[r] * rnq4[r] * rdv;
            const float x0 = mm + 0.95f;
            breg[r] += __expf(x0 * x0 * cc0);
            float g = rintf((mm + 0.85f) * 10.f);
            g = fminf(fmaxf(g, 0.f), 18.f);
            float mu = fmaf(g, 0.1f, -0.85f);
            int ks = (int)g + 1;
            if (mm > 0.975f) { mu = 1.0f; ks = 20; }
            const float xs = mm - mu;
            const float es = __expf(xs * xs * ccs);
            if (es > 0.f) atomicAdd(&phis[qt * 16 + quad * 4 + r][ks], es);
        }
        __syncthreads();
    }

    // ---- broad-bin: reduce breg across the 16 lanes sharing each q
    #pragma unroll
    for (int r = 0; r < 4; ++r) {
        float v = breg[r];
        v += __shfl_xor(v, 1, 16);
        v += __shfl_xor(v, 2, 16);
        v += __shfl_xor(v, 4, 16);
        v += __shfl_xor(v, 8, 16);
        if (l15 == 0) atomicAdd(&phis[qt * 16 + quad * 4 + r][0], v);
    }
    __syncthreads();

    // ---- ko[k] = sum_q log1p(phis[q][k])  (shfl-reduced over 32-lane groups)
    for (int p = t; p < K_NUM * Q_LEN; p += 256) {
        const int q = p & 31;
        const int k = p >> 5;
        float l = log1pf(phis[q][k]);
        l += __shfl_xor(l, 1, 32);
        l += __shfl_xor(l, 2, 32);
        l += __shfl_xor(l, 4, 32);
        l += __shfl_xor(l, 8, 32);
        l += __shfl_xor(l, 16, 32);
        if (q == 0) ko[k] = l;
    }
    __syncthreads();

    // ---- MLP 21 -> 10 -> 5 -> 1 (thread 0)
    if (t == 0) {
        float x1v[10];
        #pragma unroll
        for (int i = 0; i < 10; ++i) {
            float s = b1[i];
            for (int k = 0; k < K_NUM; ++k) {
                float v = ko[k] > 0.f ? ko[k] : 0.f;
                s = fmaf(v, w1[k * 10 + i], s);
            }
            x1v[i] = s;
        }
        float x2v[5];
        #pragma unroll
        for (int i = 0; i < 5; ++i) {
            float s = b2[i];
            #pragma unroll
            for (int k = 0; k < 10; ++k) {
                float v = x1v[k] > 0.f ? x1v[k] : 0.f;
                s = fmaf(v, w2[k * 5 + i], s);
            }
            x2v[i] = s;
        }
        float s3 = b3[0];
        #pragma unroll
        for (int k = 0; k < 5; ++k) {
            float v = x2v[k] > 0.f ? x2v[k] : 0.f;
            s3 = fmaf(v, w3[k], s3);
        }
        logits[pair * B_SIZE + b] = s3;
    }
}

__global__ void knrm_final(const float* __restrict__ logits, float* __restrict__ out)
{
    const int b = blockIdx.x * blockDim.x + threadIdx.x;
    if (b < B_SIZE) {
        const float dl = logits[b] - logits[B_SIZE + b];
        out[b] = 1.0f / (1.0f + __expf(-dl));
    }
}

extern "C" void kernel_launch(void* const* d_in, const int* in_sizes, int n_in,
                              void* d_out, int out_size, void* d_ws, size_t ws_size,
                              hipStream_t stream)
{
    const float* emb = (const float*)d_in[0];
    const float* w1  = (const float*)d_in[1];
    const float* b1  = (const float*)d_in[2];
    const float* w2  = (const float*)d_in[3];
    const float* b2  = (const float*)d_in[4];
    const float* w3  = (const float*)d_in[5];
    const float* b3  = (const float*)d_in[6];
    const int*   q1  = (const int*)d_in[7];
    const int*   d1  = (const int*)d_in[8];
    const int*   q2  = (const int*)d_in[9];
    const int*   d2  = (const int*)d_in[10];

    float* logits = (float*)d_ws;          // [2][B_SIZE]
    float* out    = (float*)d_out;         // [B_SIZE]

    dim3 grid(B_SIZE, 2);
    knrm_main<<<grid, 256, 0, stream>>>(emb, q1, d1, q2, d2,
                                        w1, b1, w2, b2, w3, b3, logits);
    knrm_final<<<(B_SIZE + 255) / 256, 256, 0, stream>>>(logits, out);
}

// Round 4
// 124.745 us; speedup vs baseline: 1.4523x; 1.0409x over previous
//
#include <hip/hip_runtime.h>
#include <math.h>

#define V_SIZE 100000
#define E_DIM  128
#define B_SIZE 512
#define Q_LEN  32
#define D_LEN  256
#define K_NUM  21

// Kernel params (faithful to the reference's swapped sigma call):
// mus ascending: [-0.95, -0.85, ..., 0.85, 0.95, 1.0]
// sigmas descending: [0.1, 0.001 x 20]  -> k=0 broad (mu=-0.95), k>=1 sharp.
//
// Nearest-bin exactness: sharp sigma=1e-3 -> exp underflows to 0.0f once
// |mm-mu| > 0.01443; sharp mus are >=0.05 apart -> at most ONE sharp bin
// nonzero per mm. broad + nearest-sharp == all 21 bins, bit-exact (R3: absmax 0).
//
// fp16-split matmul: a = hi + lo (both fp16). hi*hi + lo*hi + hi*lo drops only
// lo*lo (<=2^-22|a||b|) -> mm error ~1e-6, fp32-class (R3: absmax 0).
//
// R4 structure: barrier-free doc loop. Each wave owns 64 docs; B-fragments are
// built in registers straight from global (lane(quad,l15) reads doc l15's
// k-slice quad*8 -> exactly the MFMA B layout). Doc norms via shfl_xor(16,32)
// across quads; epilogue needs col=l15's norm = the lane's own. A staged once
// in LDS in FRAGMENT ORDER [qt][s][lane] -> lane-linear conflict-free b128.

typedef _Float16 half8_t  __attribute__((ext_vector_type(8)));
typedef float    float4_t __attribute__((ext_vector_type(4)));

__global__ __launch_bounds__(256, 4) void knrm_main(
    const float* __restrict__ emb,
    const int* __restrict__ q1, const int* __restrict__ d1,
    const int* __restrict__ q2, const int* __restrict__ d2,
    const float* __restrict__ w1, const float* __restrict__ b1,
    const float* __restrict__ w2, const float* __restrict__ b2,
    const float* __restrict__ w3, const float* __restrict__ b3,
    float* __restrict__ logits)
{
    const int b    = blockIdx.x;
    const int pair = blockIdx.y;
    const int t    = threadIdx.x;            // 0..255
    const int* __restrict__ qidx = pair ? q2 : q1;
    const int* __restrict__ didx = pair ? d2 : d1;

    __shared__ half8_t AfH[2][4][64];        // [qt][s][lane] query hi fragments
    __shared__ half8_t AfL[2][4][64];        // lo fragments
    __shared__ float rnq[Q_LEN];
    __shared__ float phis[Q_LEN][22];        // k = 0..20
    __shared__ float ko[K_NUM];

    const int lane = t & 63;
    const int w    = t >> 6;                 // wave 0..3 -> owns docs w*64..+63
    const int quad = lane >> 4;
    const int l15  = lane & 15;

    // ---- phis init
    for (int i = t; i < Q_LEN * 22; i += 256) ((float*)phis)[i] = 0.f;

    // ---- Phase 1: queries -> fp16 hi/lo fragments in LDS (+ rnq)
    {
        const int qr = t >> 3;               // 0..31
        const int qc = t & 7;                // 16-float column block
        int qi = qidx[b * Q_LEN + qr];
        qi = min(max(qi, 0), V_SIZE - 1);
        const float4* src = (const float4*)(emb + (size_t)qi * E_DIM) + qc * 4;
        float4 v0 = src[0], v1 = src[1], v2 = src[2], v3 = src[3];
        float fv[16] = {v0.x,v0.y,v0.z,v0.w, v1.x,v1.y,v1.z,v1.w,
                        v2.x,v2.y,v2.z,v2.w, v3.x,v3.y,v3.z,v3.w};
        float ss = 0.f;
        half8_t h0, h1, l0, l1;
        #pragma unroll
        for (int j = 0; j < 8; ++j) {
            ss = fmaf(fv[j], fv[j], ss);
            _Float16 h = (_Float16)fv[j];
            h0[j] = h; l0[j] = (_Float16)(fv[j] - (float)h);
        }
        #pragma unroll
        for (int j = 0; j < 8; ++j) {
            ss = fmaf(fv[8 + j], fv[8 + j], ss);
            _Float16 h = (_Float16)fv[8 + j];
            h1[j] = h; l1[j] = (_Float16)(fv[8 + j] - (float)h);
        }
        // fragment-order store: k-base qc*16 -> s = qc>>1, quad = (qc&1)*2 (+1)
        const int qt  = qr >> 4;
        const int lr  = qr & 15;
        const int s   = qc >> 1;
        const int qd0 = (qc & 1) * 2;
        AfH[qt][s][qd0 * 16 + lr]       = h0;
        AfH[qt][s][(qd0 + 1) * 16 + lr] = h1;
        AfL[qt][s][qd0 * 16 + lr]       = l0;
        AfL[qt][s][(qd0 + 1) * 16 + lr] = l1;
        ss += __shfl_xor(ss, 1, 8);
        ss += __shfl_xor(ss, 2, 8);
        ss += __shfl_xor(ss, 4, 8);
        if (qc == 0) rnq[qr] = 1.0f / fmaxf(sqrtf(ss), 1e-8f);
    }
    __syncthreads();

    float rnqv[8];
    #pragma unroll
    for (int i = 0; i < 8; ++i) rnqv[i] = rnq[(i >> 2) * 16 + quad * 4 + (i & 3)];

    const float cc0 = -0.5f / (0.1f * 0.1f);
    const float ccs = -0.5f / (0.001f * 0.001f);
    float breg[8] = {0.f,0.f,0.f,0.f,0.f,0.f,0.f,0.f};

    // ---- doc indices: wave's 4 chunks, own row = l15
    int dix[4];
    #pragma unroll
    for (int c = 0; c < 4; ++c) {
        int di = didx[b * D_LEN + w * 64 + c * 16 + l15];
        dix[c] = min(max(di, 0), V_SIZE - 1);
    }

    half8_t bh[4], bl[4];
    float rnd;

    // convert helper: 8x float4 (k-slices s*32+quad*8) -> B frags + own-row norm
    auto convert = [&](const float4* v) {
        float ss = 0.f;
        #pragma unroll
        for (int s = 0; s < 4; ++s) {
            float f[8] = {v[2*s].x, v[2*s].y, v[2*s].z, v[2*s].w,
                          v[2*s+1].x, v[2*s+1].y, v[2*s+1].z, v[2*s+1].w};
            half8_t h, l;
            #pragma unroll
            for (int j = 0; j < 8; ++j) {
                ss = fmaf(f[j], f[j], ss);
                _Float16 hh = (_Float16)f[j];
                h[j] = hh; l[j] = (_Float16)(f[j] - (float)hh);
            }
            bh[s] = h; bl[s] = l;
        }
        ss += __shfl_xor(ss, 16);   // quad bit 0
        ss += __shfl_xor(ss, 32);   // quad bit 1
        rnd = 1.0f / fmaxf(sqrtf(ss), 1e-8f);
    };

    // prologue: chunk 0
    {
        const float4* dr = (const float4*)(emb + (size_t)dix[0] * E_DIM) + quad * 2;
        float4 cur[8];
        #pragma unroll
        for (int s = 0; s < 4; ++s) { cur[2*s] = dr[s*8]; cur[2*s+1] = dr[s*8+1]; }
        convert(cur);
    }

    // ---- barrier-free doc loop: 4 chunks of 16 docs
    #pragma unroll
    for (int c = 0; c < 4; ++c) {
        float4 nx[8];
        if (c < 3) {
            const float4* dr = (const float4*)(emb + (size_t)dix[c+1] * E_DIM) + quad * 2;
            #pragma unroll
            for (int s = 0; s < 4; ++s) { nx[2*s] = dr[s*8]; nx[2*s+1] = dr[s*8+1]; }
        }

        float4_t acc0 = {0.f,0.f,0.f,0.f}, acc1 = {0.f,0.f,0.f,0.f};
        #pragma unroll
        for (int s = 0; s < 4; ++s) {
            half8_t a0h = AfH[0][s][lane], a0l = AfL[0][s][lane];
            half8_t a1h = AfH[1][s][lane], a1l = AfL[1][s][lane];
            acc0 = __builtin_amdgcn_mfma_f32_16x16x32_f16(a0h, bh[s], acc0, 0, 0, 0);
            acc1 = __builtin_amdgcn_mfma_f32_16x16x32_f16(a1h, bh[s], acc1, 0, 0, 0);
            acc0 = __builtin_amdgcn_mfma_f32_16x16x32_f16(a0l, bh[s], acc0, 0, 0, 0);
            acc1 = __builtin_amdgcn_mfma_f32_16x16x32_f16(a1l, bh[s], acc1, 0, 0, 0);
            acc0 = __builtin_amdgcn_mfma_f32_16x16x32_f16(a0h, bl[s], acc0, 0, 0, 0);
            acc1 = __builtin_amdgcn_mfma_f32_16x16x32_f16(a1h, bl[s], acc1, 0, 0, 0);
        }

        // epilogue: mm -> broad reg-accum + nearest sharp bin atomic
        #pragma unroll
        for (int qt = 0; qt < 2; ++qt) {
            const float4_t acc = qt ? acc1 : acc0;
            #pragma unroll
            for (int r = 0; r < 4; ++r) {
                const float mm = acc[r] * rnqv[qt*4 + r] * rnd;
                const float x0 = mm + 0.95f;
                breg[qt*4 + r] += __expf(x0 * x0 * cc0);
                float g = rintf((mm + 0.85f) * 10.f);
                g = fminf(fmaxf(g, 0.f), 18.f);
                float mu = fmaf(g, 0.1f, -0.85f);
                int ks = (int)g + 1;
                if (mm > 0.975f) { mu = 1.0f; ks = 20; }
                const float xs = mm - mu;
                const float es = __expf(xs * xs * ccs);
                if (es > 0.f) atomicAdd(&phis[qt*16 + quad*4 + r][ks], es);
            }
        }

        if (c < 3) convert(nx);   // next chunk's frags + rnd (after epilogue used rnd)
    }

    // ---- broad-bin: reduce across the 16 lanes sharing each q
    #pragma unroll
    for (int i = 0; i < 8; ++i) {
        float v = breg[i];
        v += __shfl_xor(v, 1, 16);
        v += __shfl_xor(v, 2, 16);
        v += __shfl_xor(v, 4, 16);
        v += __shfl_xor(v, 8, 16);
        if (l15 == 0) atomicAdd(&phis[(i >> 2) * 16 + quad * 4 + (i & 3)][0], v);
    }
    __syncthreads();

    // ---- ko[k] = sum_q log1p(phis[q][k])
    for (int p = t; p < K_NUM * Q_LEN; p += 256) {
        const int q = p & 31;
        const int k = p >> 5;
        float l = log1pf(phis[q][k]);
        l += __shfl_xor(l, 1, 32);
        l += __shfl_xor(l, 2, 32);
        l += __shfl_xor(l, 4, 32);
        l += __shfl_xor(l, 8, 32);
        l += __shfl_xor(l, 16, 32);
        if (q == 0) ko[k] = l;
    }
    __syncthreads();

    // ---- MLP 21 -> 10 -> 5 -> 1 (thread 0)
    if (t == 0) {
        float x1v[10];
        #pragma unroll
        for (int i = 0; i < 10; ++i) {
            float s = b1[i];
            for (int k = 0; k < K_NUM; ++k) {
                float v = ko[k] > 0.f ? ko[k] : 0.f;
                s = fmaf(v, w1[k * 10 + i], s);
            }
            x1v[i] = s;
        }
        float x2v[5];
        #pragma unroll
        for (int i = 0; i < 5; ++i) {
            float s = b2[i];
            #pragma unroll
            for (int k = 0; k < 10; ++k) {
                float v = x1v[k] > 0.f ? x1v[k] : 0.f;
                s = fmaf(v, w2[k * 5 + i], s);
            }
            x2v[i] = s;
        }
        float s3 = b3[0];
        #pragma unroll
        for (int k = 0; k < 5; ++k) {
            float v = x2v[k] > 0.f ? x2v[k] : 0.f;
            s3 = fmaf(v, w3[k], s3);
        }
        logits[pair * B_SIZE + b] = s3;
    }
}

__global__ void knrm_final(const float* __restrict__ logits, float* __restrict__ out)
{
    const int b = blockIdx.x * blockDim.x + threadIdx.x;
    if (b < B_SIZE) {
        const float dl = logits[b] - logits[B_SIZE + b];
        out[b] = 1.0f / (1.0f + __expf(-dl));
    }
}

extern "C" void kernel_launch(void* const* d_in, const int* in_sizes, int n_in,
                              void* d_out, int out_size, void* d_ws, size_t ws_size,
                              hipStream_t stream)
{
    const float* emb = (const float*)d_in[0];
    const float* w1  = (const float*)d_in[1];
    const float* b1  = (const float*)d_in[2];
    const float* w2  = (const float*)d_in[3];
    const float* b2  = (const float*)d_in[4];
    const float* w3  = (const float*)d_in[5];
    const float* b3  = (const float*)d_in[6];
    const int*   q1  = (const int*)d_in[7];
    const int*   d1  = (const int*)d_in[8];
    const int*   q2  = (const int*)d_in[9];
    const int*   d2  = (const int*)d_in[10];

    float* logits = (float*)d_ws;          // [2][B_SIZE]
    float* out    = (float*)d_out;         // [B_SIZE]

    dim3 grid(B_SIZE, 2);
    knrm_main<<<grid, 256, 0, stream>>>(emb, q1, d1, q2, d2,
                                        w1, b1, w2, b2, w3, b3, logits);
    knrm_final<<<(B_SIZE + 255) / 256, 256, 0, stream>>>(logits, out);
}